// Round 2
// baseline (67.476 us; speedup 1.0000x reference)
//
#include <hip/hip_runtime.h>

#define NPTS 8192
#define DIM  512
#define NK   64
#define DC   (DIM/4)   // 128 float4 chunks per row
#define KC   32        // float4 chunks per LDS stage (128 dims, 32 KB)
#define PPW  4         // points per wave
#define WPB  4         // waves per block

// ---------------------------------------------------------------------------
// Prep: gather the 64 centroid rows, store transposed d-major as ct4[dc][k]
// (so the main kernel's lane-k read of ct4[dc*64+k] is a coalesced 1KB wave
// read), and compute per-centroid sum / sum-of-squares.
// ---------------------------------------------------------------------------
__global__ __launch_bounds__(64) void prep_kernel(
    const float* __restrict__ f, const int* __restrict__ cid,
    float4* __restrict__ ct4, float* __restrict__ sqc, float* __restrict__ sc)
{
    const int k = blockIdx.x;      // one block (one wave) per centroid
    const int lane = threadIdx.x;  // 64 lanes
    const float4* row = (const float4*)(f + (size_t)cid[k] * DIM);
    float4 a = row[lane * 2];
    float4 b = row[lane * 2 + 1];
    ct4[(lane * 2) * NK + k]     = a;
    ct4[(lane * 2 + 1) * NK + k] = b;
    float s = a.x + a.y + a.z + a.w + b.x + b.y + b.z + b.w;
    float q = a.x*a.x + a.y*a.y + a.z*a.z + a.w*a.w
            + b.x*b.x + b.y*b.y + b.z*b.z + b.w*b.w;
    #pragma unroll
    for (int off = 32; off; off >>= 1) {
        s += __shfl_xor(s, off);
        q += __shfl_xor(q, off);
    }
    if (lane == 0) { sqc[k] = q; sc[k] = s; }
}

// ---------------------------------------------------------------------------
// Main: 512 blocks x 4 waves; each wave owns 4 consecutive points, lane <-> k.
// Centroid matrix staged through LDS in 32KB chunks (ds_read_b128, no L2
// round-trip in the inner loop). 16 independent FMAs per dc step for ILP.
// ---------------------------------------------------------------------------
__global__ __launch_bounds__(256) void main_kernel(
    const float* __restrict__ f, const int* __restrict__ cid,
    const float4* __restrict__ ct4, const float* __restrict__ sqc,
    const float* __restrict__ sc, float* __restrict__ out)
{
    __shared__ float4 ct_lds[KC * NK];   // 32 KB

    const int lane = threadIdx.x & 63;
    const int wave = threadIdx.x >> 6;
    const int gw   = blockIdx.x * WPB + wave;   // global wave id, 0..2047
    const int base = gw * PPW;                  // first of this wave's points

    const float mySq  = sqc[lane];
    const float myS   = sc[lane];
    const int   myCid = cid[lane];

    // Per-point row stats (sum, sum-of-squares): coalesced 2KB wave read +
    // butterfly. Also warms L1/L2 with the rows the dot loop will re-read.
    float srow[PPW], qrow[PPW];
    #pragma unroll
    for (int p = 0; p < PPW; ++p) {
        const float4* rp = (const float4*)(f + (size_t)(base + p) * DIM);
        float4 a = rp[lane * 2];
        float4 b = rp[lane * 2 + 1];
        float s = a.x + a.y + a.z + a.w + b.x + b.y + b.z + b.w;
        float q = a.x*a.x + a.y*a.y + a.z*a.z + a.w*a.w
                + b.x*b.x + b.y*b.y + b.z*b.z + b.w*b.w;
        #pragma unroll
        for (int off = 32; off; off >>= 1) {
            s += __shfl_xor(s, off);
            q += __shfl_xor(q, off);
        }
        srow[p] = s; qrow[p] = q;
    }

    // Dot products: acc[p] = dot(f[base+p], centroid[lane])
    float acc[PPW] = {0.f, 0.f, 0.f, 0.f};
    const float* fb = f + (size_t)base * DIM;

    for (int ch = 0; ch < DC / KC; ++ch) {
        // Stage 32KB chunk of ct4 (contiguous in global: dc-major) into LDS.
        const float4* src = ct4 + ch * KC * NK;
        #pragma unroll
        for (int j = 0; j < (KC * NK) / 256; ++j)
            ct_lds[threadIdx.x + 256 * j] = src[threadIdx.x + 256 * j];
        __syncthreads();

        #pragma unroll 4
        for (int dc = 0; dc < KC; ++dc) {
            float4 c4 = ct_lds[dc * NK + lane];
            #pragma unroll
            for (int p = 0; p < PPW; ++p) {
                const float4 fp =
                    *(const float4*)(fb + p * DIM + (ch * KC + dc) * 4);
                acc[p] = fmaf(fp.x, c4.x, acc[p]);
                acc[p] = fmaf(fp.y, c4.y, acc[p]);
                acc[p] = fmaf(fp.z, c4.z, acc[p]);
                acc[p] = fmaf(fp.w, c4.w, acc[p]);
            }
        }
        __syncthreads();
    }

    // Epilogue: distance, min/argmin (first-index tie-break via packed key),
    // centroid override (last-write-wins = highest matching k), energy.
    float esum = 0.f;
    float yv   = 0.f;
    #pragma unroll
    for (int p = 0; p < PPW; ++p) {
        const int i = base + p;
        float d2 = qrow[p] + mySq - 2.0f * acc[p]
                 + 2.0e-6f * (srow[p] - myS) + 5.12e-10f;
        float dist = sqrtf(fmaxf(d2, 0.0f));
        // dist >= 0 -> IEEE bits are order-preserving as uint.
        unsigned long long key =
            (((unsigned long long)__float_as_uint(dist)) << 6)
            | (unsigned long long)lane;
        #pragma unroll
        for (int off = 32; off; off >>= 1) {
            unsigned long long o = __shfl_xor(key, off);
            key = (o < key) ? o : key;
        }
        float dmin = __uint_as_float((unsigned)(key >> 6));
        float y    = (float)(unsigned)(key & 63ull);
        unsigned long long ball = __ballot(myCid == i);
        if (ball) y = (float)(63 - __clzll(ball));  // last write wins (max k)
        esum += dmin;
        if (lane == p) yv = y;
    }
    if (lane == 0) atomicAdd(out, -esum);
    if (lane < PPW) out[1 + base + lane] = yv;
}

extern "C" void kernel_launch(void* const* d_in, const int* in_sizes, int n_in,
                              void* d_out, int out_size, void* d_ws, size_t ws_size,
                              hipStream_t stream) {
    const float* f   = (const float*)d_in[0];
    const int*   cid = (const int*)d_in[1];
    float*       out = (float*)d_out;

    float4* ct4 = (float4*)d_ws;                                    // 128 KB
    float*  sqc = (float*)((char*)d_ws + DC * NK * sizeof(float4)); // +64 f
    float*  sc  = sqc + NK;                                         // +64 f

    // Zero the energy accumulator every launch (graph-capture-safe).
    hipMemsetAsync(d_out, 0, sizeof(float), stream);

    prep_kernel<<<NK, 64, 0, stream>>>(f, cid, ct4, sqc, sc);
    main_kernel<<<NPTS / (PPW * WPB), WPB * 64, 0, stream>>>(
        f, cid, ct4, sqc, sc, out);
}

// Round 3
// 39.799 us; speedup vs baseline: 1.6954x; 1.6954x over previous
//
#include <hip/hip_runtime.h>

#define NPTS  8192
#define DIM   512
#define NK    64
#define BM    32
#define BK    32            // dims per staged chunk
#define HALFK 256           // dims per K-half
#define NCHUNK (HALFK/BK)   // 8
#define AP    36            // padded A row stride in floats (144B, 16B-aligned)

// ---------------------------------------------------------------------------
// Prep: gather centroid rows into transposed ctT[d][n] (so main's B staging is
// a linear copy) and compute per-centroid stats sqc/sc.
// ---------------------------------------------------------------------------
__global__ __launch_bounds__(64) void prep_kernel(
    const float* __restrict__ f, const int* __restrict__ cid,
    float* __restrict__ ctT, float* __restrict__ sqc, float* __restrict__ sc)
{
    const int k = blockIdx.x;      // one wave per centroid
    const int lane = threadIdx.x;
    const float* row = f + (size_t)cid[k] * DIM;
    float4 a = *(const float4*)(row + lane * 8);
    float4 b = *(const float4*)(row + lane * 8 + 4);
    const int d = lane * 8;
    ctT[(d+0)*NK + k] = a.x;  ctT[(d+1)*NK + k] = a.y;
    ctT[(d+2)*NK + k] = a.z;  ctT[(d+3)*NK + k] = a.w;
    ctT[(d+4)*NK + k] = b.x;  ctT[(d+5)*NK + k] = b.y;
    ctT[(d+6)*NK + k] = b.z;  ctT[(d+7)*NK + k] = b.w;
    float s = a.x+a.y+a.z+a.w + b.x+b.y+b.z+b.w;
    float q = a.x*a.x+a.y*a.y+a.z*a.z+a.w*a.w
            + b.x*b.x+b.y*b.y+b.z*b.z+b.w*b.w;
    #pragma unroll
    for (int off = 32; off; off >>= 1) {
        s += __shfl_xor(s, off);
        q += __shfl_xor(q, off);
    }
    if (lane == 0) { sqc[k] = q; sc[k] = s; }
}

// ---------------------------------------------------------------------------
// Main: GEMM-tiled. 256 blocks x 512 threads. Tile BM=32 x NK=64; the two
// 256-thread halves split K (256 dims each). Coalesced staging, reg-prefetch,
// fused stats + distance + argmin + override + energy epilogue.
// Thread map (within a half): tn = u&15 (4 centroids), tm = u>>4 (2 rows).
// ---------------------------------------------------------------------------
__global__ __launch_bounds__(512) void main_kernel(
    const float* __restrict__ f, const int* __restrict__ cid,
    const float* __restrict__ ctT, const float* __restrict__ sqc,
    const float* __restrict__ sc, float* __restrict__ out)
{
    __shared__ float Alds[2][BM * AP];     // 2 x 4.6 KB
    __shared__ float Blds[2][BK * NK];     // 2 x 8 KB
    __shared__ float srow[BM], qrow[BM];
    __shared__ float sqc_l[NK], sc_l[NK];
    __shared__ int   cid_l[NK];

    const int t    = threadIdx.x;
    const int half = t >> 8;
    const int u    = t & 255;
    const int tn   = u & 15;
    const int tm   = u >> 4;        // 0..15
    const int m0   = tm * 2;
    const int mrow = blockIdx.x * BM;

    if (t < NK) { sqc_l[t] = sqc[t]; sc_l[t] = sc[t]; cid_l[t] = cid[t]; }

    // staging roles
    const int arow = u >> 3;        // 0..31  (A row within tile)
    const int aq   = u & 7;         // float4 quad within 32-dim chunk
    const int brow = u >> 4;        // 0..15  (B row within chunk; +16 second)
    const float* aptr = f + (size_t)(mrow + arow) * DIM + half * HALFK + aq * 4;
    const float* bptr = ctT + (size_t)(half * HALFK + brow) * NK + tn * 4;

    float* Al = Alds[half];
    float* Bl = Blds[half];

    float sp = 0.f, qp = 0.f;
    float acc[2][4] = {{0.f,0.f,0.f,0.f},{0.f,0.f,0.f,0.f}};

    // prologue: stage chunk 0
    {
        float4 pa  = *(const float4*)aptr;
        float4 pb0 = *(const float4*)bptr;
        float4 pb1 = *(const float4*)(bptr + 16 * NK);
        *(float4*)(Al + arow * AP + aq * 4)        = pa;
        *(float4*)(Bl + brow * NK + tn * 4)        = pb0;
        *(float4*)(Bl + (brow + 16) * NK + tn * 4) = pb1;
        sp += pa.x+pa.y+pa.z+pa.w;
        qp += pa.x*pa.x+pa.y*pa.y+pa.z*pa.z+pa.w*pa.w;
    }
    __syncthreads();

    for (int c = 0; c < NCHUNK; ++c) {
        float4 na, nb0, nb1;
        if (c + 1 < NCHUNK) {   // issue next-chunk loads before compute (T14)
            na  = *(const float4*)(aptr + (c + 1) * BK);
            nb0 = *(const float4*)(bptr + (size_t)(c + 1) * BK * NK);
            nb1 = *(const float4*)(bptr + (size_t)((c + 1) * BK + 16) * NK);
        }
        #pragma unroll
        for (int q = 0; q < 8; ++q) {
            float4 a0 = *(const float4*)(Al + (m0 + 0) * AP + q * 4);
            float4 a1 = *(const float4*)(Al + (m0 + 1) * AP + q * 4);
            const float av0[4] = {a0.x, a0.y, a0.z, a0.w};
            const float av1[4] = {a1.x, a1.y, a1.z, a1.w};
            #pragma unroll
            for (int kk = 0; kk < 4; ++kk) {
                float4 b = *(const float4*)(Bl + (q * 4 + kk) * NK + tn * 4);
                acc[0][0] = fmaf(av0[kk], b.x, acc[0][0]);
                acc[0][1] = fmaf(av0[kk], b.y, acc[0][1]);
                acc[0][2] = fmaf(av0[kk], b.z, acc[0][2]);
                acc[0][3] = fmaf(av0[kk], b.w, acc[0][3]);
                acc[1][0] = fmaf(av1[kk], b.x, acc[1][0]);
                acc[1][1] = fmaf(av1[kk], b.y, acc[1][1]);
                acc[1][2] = fmaf(av1[kk], b.z, acc[1][2]);
                acc[1][3] = fmaf(av1[kk], b.w, acc[1][3]);
            }
        }
        __syncthreads();          // all reads of this chunk done
        if (c + 1 < NCHUNK) {
            *(float4*)(Al + arow * AP + aq * 4)        = na;
            *(float4*)(Bl + brow * NK + tn * 4)        = nb0;
            *(float4*)(Bl + (brow + 16) * NK + tn * 4) = nb1;
            sp += na.x+na.y+na.z+na.w;
            qp += na.x*na.x+na.y*na.y+na.z*na.z+na.w*na.w;
        }
        __syncthreads();          // next chunk staged
    }

    // row-stats: reduce the 8 quad-threads of each row (consecutive lanes)
    #pragma unroll
    for (int off = 1; off < 8; off <<= 1) {
        sp += __shfl_xor(sp, off);
        qp += __shfl_xor(qp, off);
    }
    if (half == 0 && aq == 0) { srow[arow] = sp; qrow[arow] = qp; }
    if (half == 1) {            // export half-1 partial dots via LDS
        float* dst = Blds[1] + u * 8;
        *(float4*)(dst)     = make_float4(acc[0][0], acc[0][1], acc[0][2], acc[0][3]);
        *(float4*)(dst + 4) = make_float4(acc[1][0], acc[1][1], acc[1][2], acc[1][3]);
    }
    __syncthreads();
    if (half == 1 && aq == 0) { srow[arow] += sp; qrow[arow] += qp; }
    __syncthreads();

    if (half == 0) {
        // combine K-halves
        const float* src = Blds[1] + u * 8;
        float4 x0 = *(const float4*)src;
        float4 x1 = *(const float4*)(src + 4);
        acc[0][0]+=x0.x; acc[0][1]+=x0.y; acc[0][2]+=x0.z; acc[0][3]+=x0.w;
        acc[1][0]+=x1.x; acc[1][1]+=x1.y; acc[1][2]+=x1.z; acc[1][3]+=x1.w;

        const float mys0 = srow[m0],   myq0 = qrow[m0];
        const float mys1 = srow[m0+1], myq1 = qrow[m0+1];

        unsigned long long key0 = ~0ull, key1 = ~0ull;
        #pragma unroll
        for (int j = 0; j < 4; ++j) {
            const int n = tn * 4 + j;
            const float cq = sqc_l[n], cs = sc_l[n];
            float d20 = myq0 + cq - 2.f * acc[0][j] + 2.0e-6f * (mys0 - cs) + 5.12e-10f;
            float d21 = myq1 + cq - 2.f * acc[1][j] + 2.0e-6f * (mys1 - cs) + 5.12e-10f;
            float di0 = sqrtf(fmaxf(d20, 0.f));
            float di1 = sqrtf(fmaxf(d21, 0.f));
            unsigned long long k0 = (((unsigned long long)__float_as_uint(di0)) << 6) | (unsigned)n;
            unsigned long long k1 = (((unsigned long long)__float_as_uint(di1)) << 6) | (unsigned)n;
            key0 = (k0 < key0) ? k0 : key0;
            key1 = (k1 < key1) ? k1 : key1;
        }
        #pragma unroll
        for (int off = 1; off < 16; off <<= 1) {
            unsigned long long o0 = __shfl_xor(key0, off);
            unsigned long long o1 = __shfl_xor(key1, off);
            key0 = (o0 < key0) ? o0 : key0;
            key1 = (o1 < key1) ? o1 : key1;
        }

        float esum = 0.f;
        if (tn == 0) {
            float dmin0 = __uint_as_float((unsigned)(key0 >> 6));
            float dmin1 = __uint_as_float((unsigned)(key1 >> 6));
            float y0 = (float)(unsigned)(key0 & 63ull);
            float y1 = (float)(unsigned)(key1 & 63ull);
            const int g0 = mrow + m0, g1 = g0 + 1;
            for (int k = 0; k < NK; ++k) {   // last write wins (ascending k)
                if (cid_l[k] == g0) y0 = (float)k;
                if (cid_l[k] == g1) y1 = (float)k;
            }
            out[1 + g0] = y0;
            out[1 + g1] = y1;
            esum = dmin0 + dmin1;
        }
        #pragma unroll
        for (int off = 1; off < 64; off <<= 1) esum += __shfl_xor(esum, off);
        if ((t & 63) == 0) atomicAdd(out, -esum);
    }
}

extern "C" void kernel_launch(void* const* d_in, const int* in_sizes, int n_in,
                              void* d_out, int out_size, void* d_ws, size_t ws_size,
                              hipStream_t stream) {
    const float* f   = (const float*)d_in[0];
    const int*   cid = (const int*)d_in[1];
    float*       out = (float*)d_out;

    float* ctT = (float*)d_ws;                       // 512*64*4 = 128 KB
    float* sqc = ctT + DIM * NK;                     // +64 floats
    float* sc  = sqc + NK;                           // +64 floats

    hipMemsetAsync(d_out, 0, sizeof(float), stream); // zero energy accumulator

    prep_kernel<<<NK, 64, 0, stream>>>(f, cid, ctT, sqc, sc);
    main_kernel<<<NPTS / BM, 512, 0, stream>>>(f, cid, ctT, sqc, sc, out);
}

// Round 4
// 37.844 us; speedup vs baseline: 1.7830x; 1.0517x over previous
//
#include <hip/hip_runtime.h>

#define NPTS  8192
#define DIM   512
#define NK    64
#define BM    32
#define BK    32            // dims per staged chunk
#define HALFK 256           // dims per K-half
#define NCHUNK (HALFK/BK)   // 8
#define AP    36            // padded A row stride in floats (144B, 16B-aligned)

// ---------------------------------------------------------------------------
// Prep: gather centroid rows into transposed ctT[d][n] (so main's B staging is
// a linear copy), compute per-centroid stats sqc/sc, and zero the energy
// accumulator (replaces a hipMemsetAsync dispatch that cost ~40us/replay).
// ---------------------------------------------------------------------------
__global__ __launch_bounds__(64) void prep_kernel(
    const float* __restrict__ f, const int* __restrict__ cid,
    float* __restrict__ ctT, float* __restrict__ sqc, float* __restrict__ sc,
    float* __restrict__ out)
{
    const int k = blockIdx.x;      // one wave per centroid
    const int lane = threadIdx.x;
    if (k == 0 && lane == 0) out[0] = 0.f;   // runs before main (stream order)
    const float* row = f + (size_t)cid[k] * DIM;
    float4 a = *(const float4*)(row + lane * 8);
    float4 b = *(const float4*)(row + lane * 8 + 4);
    const int d = lane * 8;
    ctT[(d+0)*NK + k] = a.x;  ctT[(d+1)*NK + k] = a.y;
    ctT[(d+2)*NK + k] = a.z;  ctT[(d+3)*NK + k] = a.w;
    ctT[(d+4)*NK + k] = b.x;  ctT[(d+5)*NK + k] = b.y;
    ctT[(d+6)*NK + k] = b.z;  ctT[(d+7)*NK + k] = b.w;
    float s = a.x+a.y+a.z+a.w + b.x+b.y+b.z+b.w;
    float q = a.x*a.x+a.y*a.y+a.z*a.z+a.w*a.w
            + b.x*b.x+b.y*b.y+b.z*b.z+b.w*b.w;
    #pragma unroll
    for (int off = 32; off; off >>= 1) {
        s += __shfl_xor(s, off);
        q += __shfl_xor(q, off);
    }
    if (lane == 0) { sqc[k] = q; sc[k] = s; }
}

// ---------------------------------------------------------------------------
// Main: GEMM-tiled. 256 blocks x 512 threads. Tile BM=32 x NK=64; the two
// 256-thread halves split K (256 dims each). Coalesced staging, reg-prefetch,
// fused stats + distance + argmin + override + energy epilogue.
// Thread map (within a half): tn = u&15 (4 centroids), tm = u>>4 (2 rows).
// ---------------------------------------------------------------------------
__global__ __launch_bounds__(512) void main_kernel(
    const float* __restrict__ f, const int* __restrict__ cid,
    const float* __restrict__ ctT, const float* __restrict__ sqc,
    const float* __restrict__ sc, float* __restrict__ out)
{
    __shared__ float Alds[2][BM * AP];     // 2 x 4.6 KB
    __shared__ float Blds[2][BK * NK];     // 2 x 8 KB
    __shared__ float srow[BM], qrow[BM];
    __shared__ float sqc_l[NK], sc_l[NK];
    __shared__ int   cid_l[NK];

    const int t    = threadIdx.x;
    const int half = t >> 8;
    const int u    = t & 255;
    const int tn   = u & 15;
    const int tm   = u >> 4;        // 0..15
    const int m0   = tm * 2;
    const int mrow = blockIdx.x * BM;

    if (t < NK) { sqc_l[t] = sqc[t]; sc_l[t] = sc[t]; cid_l[t] = cid[t]; }

    // staging roles
    const int arow = u >> 3;        // 0..31  (A row within tile)
    const int aq   = u & 7;         // float4 quad within 32-dim chunk
    const int brow = u >> 4;        // 0..15  (B row within chunk; +16 second)
    const float* aptr = f + (size_t)(mrow + arow) * DIM + half * HALFK + aq * 4;
    const float* bptr = ctT + (size_t)(half * HALFK + brow) * NK + tn * 4;

    float* Al = Alds[half];
    float* Bl = Blds[half];

    float sp = 0.f, qp = 0.f;
    float acc[2][4] = {{0.f,0.f,0.f,0.f},{0.f,0.f,0.f,0.f}};

    // prologue: stage chunk 0
    {
        float4 pa  = *(const float4*)aptr;
        float4 pb0 = *(const float4*)bptr;
        float4 pb1 = *(const float4*)(bptr + 16 * NK);
        *(float4*)(Al + arow * AP + aq * 4)        = pa;
        *(float4*)(Bl + brow * NK + tn * 4)        = pb0;
        *(float4*)(Bl + (brow + 16) * NK + tn * 4) = pb1;
        sp += pa.x+pa.y+pa.z+pa.w;
        qp += pa.x*pa.x+pa.y*pa.y+pa.z*pa.z+pa.w*pa.w;
    }
    __syncthreads();

    for (int c = 0; c < NCHUNK; ++c) {
        float4 na, nb0, nb1;
        if (c + 1 < NCHUNK) {   // issue next-chunk loads before compute (T14)
            na  = *(const float4*)(aptr + (c + 1) * BK);
            nb0 = *(const float4*)(bptr + (size_t)(c + 1) * BK * NK);
            nb1 = *(const float4*)(bptr + (size_t)((c + 1) * BK + 16) * NK);
        }
        #pragma unroll
        for (int q = 0; q < 8; ++q) {
            float4 a0 = *(const float4*)(Al + (m0 + 0) * AP + q * 4);
            float4 a1 = *(const float4*)(Al + (m0 + 1) * AP + q * 4);
            const float av0[4] = {a0.x, a0.y, a0.z, a0.w};
            const float av1[4] = {a1.x, a1.y, a1.z, a1.w};
            #pragma unroll
            for (int kk = 0; kk < 4; ++kk) {
                float4 b = *(const float4*)(Bl + (q * 4 + kk) * NK + tn * 4);
                acc[0][0] = fmaf(av0[kk], b.x, acc[0][0]);
                acc[0][1] = fmaf(av0[kk], b.y, acc[0][1]);
                acc[0][2] = fmaf(av0[kk], b.z, acc[0][2]);
                acc[0][3] = fmaf(av0[kk], b.w, acc[0][3]);
                acc[1][0] = fmaf(av1[kk], b.x, acc[1][0]);
                acc[1][1] = fmaf(av1[kk], b.y, acc[1][1]);
                acc[1][2] = fmaf(av1[kk], b.z, acc[1][2]);
                acc[1][3] = fmaf(av1[kk], b.w, acc[1][3]);
            }
        }
        __syncthreads();          // all reads of this chunk done
        if (c + 1 < NCHUNK) {
            *(float4*)(Al + arow * AP + aq * 4)        = na;
            *(float4*)(Bl + brow * NK + tn * 4)        = nb0;
            *(float4*)(Bl + (brow + 16) * NK + tn * 4) = nb1;
            sp += na.x+na.y+na.z+na.w;
            qp += na.x*na.x+na.y*na.y+na.z*na.z+na.w*na.w;
        }
        __syncthreads();          // next chunk staged
    }

    // row-stats: reduce the 8 quad-threads of each row (consecutive lanes)
    #pragma unroll
    for (int off = 1; off < 8; off <<= 1) {
        sp += __shfl_xor(sp, off);
        qp += __shfl_xor(qp, off);
    }
    if (half == 0 && aq == 0) { srow[arow] = sp; qrow[arow] = qp; }
    if (half == 1) {            // export half-1 partial dots via LDS
        float* dst = Blds[1] + u * 8;
        *(float4*)(dst)     = make_float4(acc[0][0], acc[0][1], acc[0][2], acc[0][3]);
        *(float4*)(dst + 4) = make_float4(acc[1][0], acc[1][1], acc[1][2], acc[1][3]);
    }
    __syncthreads();
    if (half == 1 && aq == 0) { srow[arow] += sp; qrow[arow] += qp; }
    __syncthreads();

    if (half == 0) {
        // combine K-halves
        const float* src = Blds[1] + u * 8;
        float4 x0 = *(const float4*)src;
        float4 x1 = *(const float4*)(src + 4);
        acc[0][0]+=x0.x; acc[0][1]+=x0.y; acc[0][2]+=x0.z; acc[0][3]+=x0.w;
        acc[1][0]+=x1.x; acc[1][1]+=x1.y; acc[1][2]+=x1.z; acc[1][3]+=x1.w;

        const float mys0 = srow[m0],   myq0 = qrow[m0];
        const float mys1 = srow[m0+1], myq1 = qrow[m0+1];

        unsigned long long key0 = ~0ull, key1 = ~0ull;
        #pragma unroll
        for (int j = 0; j < 4; ++j) {
            const int n = tn * 4 + j;
            const float cq = sqc_l[n], cs = sc_l[n];
            float d20 = myq0 + cq - 2.f * acc[0][j] + 2.0e-6f * (mys0 - cs) + 5.12e-10f;
            float d21 = myq1 + cq - 2.f * acc[1][j] + 2.0e-6f * (mys1 - cs) + 5.12e-10f;
            float di0 = sqrtf(fmaxf(d20, 0.f));
            float di1 = sqrtf(fmaxf(d21, 0.f));
            unsigned long long k0 = (((unsigned long long)__float_as_uint(di0)) << 6) | (unsigned)n;
            unsigned long long k1 = (((unsigned long long)__float_as_uint(di1)) << 6) | (unsigned)n;
            key0 = (k0 < key0) ? k0 : key0;
            key1 = (k1 < key1) ? k1 : key1;
        }
        #pragma unroll
        for (int off = 1; off < 16; off <<= 1) {
            unsigned long long o0 = __shfl_xor(key0, off);
            unsigned long long o1 = __shfl_xor(key1, off);
            key0 = (o0 < key0) ? o0 : key0;
            key1 = (o1 < key1) ? o1 : key1;
        }

        float esum = 0.f;
        if (tn == 0) {
            float dmin0 = __uint_as_float((unsigned)(key0 >> 6));
            float dmin1 = __uint_as_float((unsigned)(key1 >> 6));
            float y0 = (float)(unsigned)(key0 & 63ull);
            float y1 = (float)(unsigned)(key1 & 63ull);
            const int g0 = mrow + m0, g1 = g0 + 1;
            for (int k = 0; k < NK; ++k) {   // last write wins (ascending k)
                if (cid_l[k] == g0) y0 = (float)k;
                if (cid_l[k] == g1) y1 = (float)k;
            }
            out[1 + g0] = y0;
            out[1 + g1] = y1;
            esum = dmin0 + dmin1;
        }
        #pragma unroll
        for (int off = 1; off < 64; off <<= 1) esum += __shfl_xor(esum, off);
        if ((t & 63) == 0) atomicAdd(out, -esum);
    }
}

extern "C" void kernel_launch(void* const* d_in, const int* in_sizes, int n_in,
                              void* d_out, int out_size, void* d_ws, size_t ws_size,
                              hipStream_t stream) {
    const float* f   = (const float*)d_in[0];
    const int*   cid = (const int*)d_in[1];
    float*       out = (float*)d_out;

    float* ctT = (float*)d_ws;                       // 512*64*4 = 128 KB
    float* sqc = ctT + DIM * NK;                     // +64 floats
    float* sc  = sqc + NK;                           // +64 floats

    prep_kernel<<<NK, 64, 0, stream>>>(f, cid, ctT, sqc, sc, out);
    main_kernel<<<NPTS / BM, 512, 0, stream>>>(f, cid, ctT, sqc, sc, out);
}